// Round 9
// baseline (6570.539 us; speedup 1.0000x reference)
//
#include <hip/hip_runtime.h>
#include <hip/hip_bf16.h>

// L=2, B=128, T=512, D=64, F=512
#define FDIM   512
#define BATCH  128
#define TSTEPS 512
#define GDIM   2048
#define NPH    (2*TSTEPS)
#define SLOT   (BATCH*FDIM)          // elements per h slot
#define POISON 0xFFFFFFFFu           // bf16 pair -NaN:-NaN — unreachable for real h

typedef __attribute__((ext_vector_type(8))) short bf16x8;   // 8 bf16 (4 VGPR) MFMA A/B frag
typedef __attribute__((ext_vector_type(4))) float f32x4;    // MFMA C/D frag

union AfU { bf16x8 v; unsigned long long q[2]; };

__device__ __forceinline__ ushort f32_to_bf16(float v) {
    union { float f; unsigned u; } c; c.f = v;
    unsigned b = c.u;
    return (ushort)((b + 0x7FFFu + ((b >> 16) & 1u)) >> 16);   // RNE
}
__device__ __forceinline__ float sigmoidf_(float x) { return 1.0f / (1.0f + expf(-x)); }

// Relaxed agent-scope (device-coherent) ops — round-4-proven substrate.
__device__ __forceinline__ unsigned long long aload64(const unsigned long long* p) {
    return __hip_atomic_load(p, __ATOMIC_RELAXED, __HIP_MEMORY_SCOPE_AGENT);
}
__device__ __forceinline__ void astore32(unsigned* p, unsigned v) {
    __hip_atomic_store(p, v, __ATOMIC_RELAXED, __HIP_MEMORY_SCOPE_AGENT);
}
__device__ __forceinline__ void astore64(unsigned long long* p, unsigned long long v) {
    __hip_atomic_store(p, v, __ATOMIC_RELAXED, __HIP_MEMORY_SCOPE_AGENT);
}

// ---------------------------------------------------------------------------
// One-time: weights -> bf16 concat layout wcat[L][2048][1024] (Wih row || Whh row),
// combined bias bc[L][2048].
// ---------------------------------------------------------------------------
__global__ __launch_bounds__(256) void convert_weights(
    const float* __restrict__ Wih0, const float* __restrict__ Whh0,
    const float* __restrict__ Wih1, const float* __restrict__ Whh1,
    const float* __restrict__ bih0, const float* __restrict__ bhh0,
    const float* __restrict__ bih1, const float* __restrict__ bhh1,
    ushort* __restrict__ wcat, float* __restrict__ bc)
{
    int idx = blockIdx.x * 256 + threadIdx.x;          // covers 2*2048*1024
    if (idx < 2 * GDIM * 1024) {
        int kk = idx & 1023;
        int r  = (idx >> 10) & 2047;
        int L  = idx >> 21;
        const float* Wih = L ? Wih1 : Wih0;
        const float* Whh = L ? Whh1 : Whh0;
        float v = (kk < 512) ? Wih[(size_t)r * 512 + kk] : Whh[(size_t)r * 512 + (kk - 512)];
        wcat[idx] = f32_to_bf16(v);
    }
    if (idx < 2 * GDIM) {
        int L = idx >> 11, r = idx & 2047;
        bc[idx] = L ? (bih1[r] + bhh1[r]) : (bih0[r] + bhh0[r]);
    }
}

// ---------------------------------------------------------------------------
// Persistent 2-layer LSTM. 256 WGs x 512 threads, 1 WG/CU. NO FLAGS:
// consumers poll the h data itself (0xFFFFFFFF poison = not-ready; real
// packed bf16 h pairs can never be -NaN:-NaN). hbuf = 4 rotating slots
// [128][512]; at phase ph: write ph&3, inp-read (ph-1)&3, own-read (ph-2)&3,
// poison (ph-3)&3 — all distinct. Poison happens in the EPILOGUE (after the
// barrier, which proves via the two inp polls that every WG passed barrier
// ph-1, i.e. no reader still uses that slot) and drains at the next barrier,
// before the same WG's other-layer waves rewrite the slot. One barrier/phase;
// LDS part buffer double-buffered by phase parity.
// ---------------------------------------------------------------------------
__global__ __launch_bounds__(512, 2) void lstm_persistent(
    const float* __restrict__ x,      // (2,128,64)
    const float* __restrict__ Winit,  // (512,64)
    const float* __restrict__ binit,  // (512,)
    const float* __restrict__ lastf,  // (128,512)
    const ushort* __restrict__ wcat,  // [2][2048][1024] bf16
    const float* __restrict__ bc,     // [2][2048]
    ushort* __restrict__ hbuf,        // [4][128][512] bf16 slots (pre-poisoned 0xFF)
    ushort* __restrict__ lfbuf,       // [128][512] bf16 (pre-poisoned 0xFF)
    float* __restrict__ out)          // (512,128,512) raw-reshape target
{
    const int tid  = threadIdx.x;
    const int lane = tid & 63;
    const int wave = tid >> 6;        // 0..7
    const int myL  = wave >> 2;       // layer this wave serves
    const int kq   = wave & 3;        // K-quarter of [inp(512) || h(512)]
    const int g    = blockIdx.x & 7;  // batch group
    const int ft   = blockIdx.x >> 3; // feature tile 0..31

    const int r16 = (tid >> 4) & 15;  // epilogue batch row within group
    const int cc  = tid & 15;         // epilogue f col within tile
    const int myB = g * 16 + r16;
    const int myF = ft * 16 + cc;

    __shared__ float part[2][4][4][16][16];   // [phase parity][kq][gate][m][n]

    // ---- prologue: initial c/h -> slots 2(L0)/3(L1), lf convert, bias, weights ----
    float c_reg;
    {
        const float* xr = x + ((size_t)myL * BATCH + myB) * 64;
        const float* wr = Winit + (size_t)myF * 64;
        float s = binit[myF];
        #pragma unroll
        for (int k = 0; k < 64; ++k) s += xr[k] * wr[k];
        c_reg = s;
        unsigned hv = f32_to_bf16(s);
        unsigned up = (unsigned)__shfl_xor((int)hv, 1);
        if (!(cc & 1))
            astore32((unsigned*)(hbuf + (size_t)(2 + myL) * SLOT + myB * FDIM + myF),
                     hv | (up << 16));
    }
    if (myL == 0) {
        float v = lastf[(size_t)myB * FDIM + myF];
        unsigned hv = f32_to_bf16(v);
        unsigned up = (unsigned)__shfl_xor((int)hv, 1);
        if (!(cc & 1))
            astore32((unsigned*)(lfbuf + (size_t)myB * FDIM + myF), hv | (up << 16));
    }
    float bias[4];
    #pragma unroll
    for (int ct = 0; ct < 4; ++ct) bias[ct] = bc[myL * GDIM + ct * FDIM + myF];

    bf16x8 bw[4][8];                                   // 128 regs of weights (VGPR/AGPR)
    {
        const int wl = lane & 15, kg0 = lane >> 4;
        #pragma unroll
        for (int ct = 0; ct < 4; ++ct) {
            const ushort* base = wcat + ((size_t)myL * GDIM + ct * FDIM + ft * 16 + wl) * 1024
                               + kq * 256 + kg0 * 8;
            #pragma unroll
            for (int ks = 0; ks < 8; ++ks)
                bw[ct][ks] = *reinterpret_cast<const bf16x8*>(base + ks * 32);
        }
    }
    #pragma unroll
    for (int ct = 0; ct < 4; ++ct)
        #pragma unroll
        for (int ks = 0; ks < 8; ++ks)
            asm volatile("" : "+v"(bw[ct][ks]));       // pin: no remat

    const int rA = lane & 15, kg = lane >> 4;

    // ---- 1024 serial phases ----
    for (int ph = 0; ph < NPH; ++ph) {
        const int L = ph & 1;
        const int t = ph >> 1;
        const bool active = (myL == L);

        if (active) {
            // source slab for this wave's K-quarter
            const ushort* srcBase = (kq < 2)
                ? ((ph == 0) ? lfbuf : hbuf + (size_t)((ph + 3) & 3) * SLOT)   // inp: ph-1
                : (hbuf + (size_t)((ph + 2) & 3) * SLOT);                      // own: ph-2
            const ushort* arow = srcBase + (size_t)(g * 16 + rA) * FDIM + (kq & 1) * 256 + kg * 8;

            // poll-load: retry until no dword is poison (fresh data implies
            // the producers of this slab completed the producing phase)
            bf16x8 af[8];
            for (;;) {
                bool ok = true;
                #pragma unroll
                for (int ks = 0; ks < 8; ++ks) {
                    AfU u;
                    u.q[0] = aload64((const unsigned long long*)(arow + ks * 32));
                    u.q[1] = aload64((const unsigned long long*)(arow + ks * 32) + 1);
                    af[ks] = u.v;
                    ok = ok && ((unsigned)u.q[0] != POISON) && ((unsigned)(u.q[0] >> 32) != POISON)
                            && ((unsigned)u.q[1] != POISON) && ((unsigned)(u.q[1] >> 32) != POISON);
                }
                if (__all((int)ok)) break;
            }

            f32x4 acc[4] = {{0,0,0,0},{0,0,0,0},{0,0,0,0},{0,0,0,0}};
            #pragma unroll
            for (int ks = 0; ks < 8; ++ks) {
                #pragma unroll
                for (int ct = 0; ct < 4; ++ct)
                    acc[ct] = __builtin_amdgcn_mfma_f32_16x16x32_bf16(af[ks], bw[ct][ks], acc[ct], 0, 0, 0);
            }
            const int n = lane & 15, q = lane >> 4;    // C map: m=q*4+j (batch), n (fcol)
            #pragma unroll
            for (int ct = 0; ct < 4; ++ct)
                #pragma unroll
                for (int j = 0; j < 4; ++j)
                    part[ph & 1][kq][ct][q * 4 + j][n] = acc[ct][j];
        }
        __syncthreads();   // part ready; also proves BOTH inp polls succeeded
                           // => all 32 WGs passed barrier(ph-1) => slot (ph-3)&3 has no readers

        if (active) {
            float gate[4];
            #pragma unroll
            for (int ct = 0; ct < 4; ++ct)
                gate[ct] = bias[ct]
                         + part[ph & 1][0][ct][r16][cc] + part[ph & 1][1][ct][r16][cc]
                         + part[ph & 1][2][ct][r16][cc] + part[ph & 1][3][ct][r16][cc];
            float ig = sigmoidf_(gate[0]);
            float fg = sigmoidf_(gate[1]);
            float gg = tanhf(gate[2]);
            float og = sigmoidf_(gate[3]);
            float cn = fg * c_reg + ig * gg;
            float hn = og * tanhf(cn);
            c_reg = cn;
            unsigned hv = f32_to_bf16(hn);
            unsigned up = (unsigned)__shfl_xor((int)hv, 1);
            if (!(cc & 1))
                astore32((unsigned*)(hbuf + (size_t)(ph & 3) * SLOT + myB * FDIM + myF),
                         hv | (up << 16));
            if (L == 1) out[((size_t)t * BATCH + myB) * FDIM + myF] = hn;

            // poison slot (ph-3)&3's OWN tile (rewritten next phase by this WG's
            // other-layer waves, after the next barrier drains these stores)
            if (kq == 0) {
                unsigned* ptile = (unsigned*)(hbuf + (size_t)((ph + 1) & 3) * SLOT);
                int idx = lane * 2;            // 128 dwords: 2 per lane
                int row = idx >> 3;            // 8 dwords per 16-col row
                int dc  = idx & 7;
                astore64((unsigned long long*)(ptile + (size_t)(g * 16 + row) * 256 + ft * 8 + dc),
                         0xFFFFFFFFFFFFFFFFull);
            }
        }
    }
}

// ---------------------------------------------------------------------------
extern "C" void kernel_launch(void* const* d_in, const int* in_sizes, int n_in,
                              void* d_out, int out_size, void* d_ws, size_t ws_size,
                              hipStream_t stream)
{
    const float* x      = (const float*)d_in[0];
    const float* lastf  = (const float*)d_in[1];
    const float* W_init = (const float*)d_in[2];
    const float* b_init = (const float*)d_in[3];
    const float* W_ih0  = (const float*)d_in[4];
    const float* W_hh0  = (const float*)d_in[5];
    const float* b_ih0  = (const float*)d_in[6];
    const float* b_hh0  = (const float*)d_in[7];
    const float* W_ih1  = (const float*)d_in[8];
    const float* W_hh1  = (const float*)d_in[9];
    const float* b_ih1  = (const float*)d_in[10];
    const float* b_hh1  = (const float*)d_in[11];
    // d_in[12..13] = W_out/b_out: dead code in the reference.
    float* out = (float*)d_out;

    char* ws = (char*)d_ws;
    size_t off = 0;
    ushort* wcat = (ushort*)(ws + off); off += (size_t)2 * GDIM * 1024 * 2;   // 8 MB
    float*  bcb  = (float*)(ws + off);  off += (size_t)2 * GDIM * 4;          // 16 KB
    ushort* hbuf = (ushort*)(ws + off); off += (size_t)4 * SLOT * 2;          // 512 KB (4 slots)
    ushort* lfb  = (ushort*)(ws + off); off += (size_t)SLOT * 2;              // 128 KB

    // poison all h slots + lfbuf (0xFF bytes = 0xFFFFFFFF dwords) every launch
    hipMemsetAsync(hbuf, 0xFF, (size_t)5 * SLOT * 2, stream);

    convert_weights<<<(2 * GDIM * 1024 + 255) / 256, 256, 0, stream>>>(
        W_ih0, W_hh0, W_ih1, W_hh1, b_ih0, b_hh0, b_ih1, b_hh1, wcat, bcb);

    lstm_persistent<<<256, 512, 0, stream>>>(
        x, W_init, b_init, lastf, wcat, bcb, hbuf, lfb, out);
}

// Round 10
// 6539.704 us; speedup vs baseline: 1.0047x; 1.0047x over previous
//
#include <hip/hip_runtime.h>
#include <hip/hip_bf16.h>

// L=2, B=128, T=512, D=64, F=512
#define FDIM   512
#define BATCH  128
#define TSTEPS 512
#define GDIM   2048
#define NPH    (2*TSTEPS)
#define SLOT   (BATCH*FDIM)

typedef __attribute__((ext_vector_type(8))) short bf16x8;   // 8 bf16 (4 VGPR) MFMA A/B frag
typedef __attribute__((ext_vector_type(4))) float f32x4;    // MFMA C/D frag

union AfU { bf16x8 v; unsigned long long q[2]; };

__device__ __forceinline__ ushort f32_to_bf16(float v) {
    union { float f; unsigned u; } c; c.f = v;
    unsigned b = c.u;
    return (ushort)((b + 0x7FFFu + ((b >> 16) & 1u)) >> 16);   // RNE
}
// Fast gate nonlinearities: v_exp + v_rcp (~1e-6 err, invisible at bf16).
// Inf-safe: __expf(+big)=inf -> fdividef->0; __expf(-big)=0.
__device__ __forceinline__ float fsigmoid(float x) {
    return __fdividef(1.0f, 1.0f + __expf(-x));
}
__device__ __forceinline__ float ftanh(float x) {
    return 1.0f - __fdividef(2.0f, __expf(2.0f * x) + 1.0f);
}

// Relaxed agent-scope (device-coherent) ops — round-4-proven substrate.
__device__ __forceinline__ unsigned long long aload64(const unsigned long long* p) {
    return __hip_atomic_load(p, __ATOMIC_RELAXED, __HIP_MEMORY_SCOPE_AGENT);
}
__device__ __forceinline__ unsigned aload32(const unsigned* p) {
    return __hip_atomic_load(p, __ATOMIC_RELAXED, __HIP_MEMORY_SCOPE_AGENT);
}
__device__ __forceinline__ void astore32(unsigned* p, unsigned v) {
    __hip_atomic_store(p, v, __ATOMIC_RELAXED, __HIP_MEMORY_SCOPE_AGENT);
}

// ---------------------------------------------------------------------------
// One-time: weights -> bf16 concat layout wcat[L][2048][1024] (Wih row || Whh row),
// combined bias bc[L][2048].
// ---------------------------------------------------------------------------
__global__ __launch_bounds__(256) void convert_weights(
    const float* __restrict__ Wih0, const float* __restrict__ Whh0,
    const float* __restrict__ Wih1, const float* __restrict__ Whh1,
    const float* __restrict__ bih0, const float* __restrict__ bhh0,
    const float* __restrict__ bih1, const float* __restrict__ bhh1,
    ushort* __restrict__ wcat, float* __restrict__ bc)
{
    int idx = blockIdx.x * 256 + threadIdx.x;          // covers 2*2048*1024
    if (idx < 2 * GDIM * 1024) {
        int kk = idx & 1023;
        int r  = (idx >> 10) & 2047;
        int L  = idx >> 21;
        const float* Wih = L ? Wih1 : Wih0;
        const float* Whh = L ? Whh1 : Whh0;
        float v = (kk < 512) ? Wih[(size_t)r * 512 + kk] : Whh[(size_t)r * 512 + (kk - 512)];
        wcat[idx] = f32_to_bf16(v);
    }
    if (idx < 2 * GDIM) {
        int L = idx >> 11, r = idx & 2047;
        bc[idx] = L ? (bih1[r] + bhh1[r]) : (bih0[r] + bhh0[r]);
    }
}

// ---------------------------------------------------------------------------
// Persistent 2-layer LSTM. 256 WGs x 512 threads, 1 WG/CU.
//   WG = (g = blockIdx&7: batch group of 16 rows, ft: 16 f-cols)
//   waves 0-3 layer 0, waves 4-7 layer 1; wave kq = K-quarter of [inp||h].
//   Weights: bw[4][8] = 128 regs/lane, asm-pinned. c-state: 1 reg/thread.
// Sync: ONE per-group counter (cache-line-isolated). Each active wave, after
// draining its own h-stores (vmcnt 0), adds +1 (agent scope). 4 waves/WG/phase
// x 32 WGs = 128/phase; init contributes 128. Consumer inp-waves (kq<2) poll
// cnt >= 128*(ph+1) then load; own-h waves never poll (their data is 2 phases
// old; this WG's inp-poll at ph-1 + barrier(ph-1) proves it complete).
// ONE __syncthreads per phase; LDS part buffer double-buffered by parity
// (part[p] rewritten at ph+2, after barrier(ph+1), after all epilogue(ph) reads).
// ---------------------------------------------------------------------------
__global__ __launch_bounds__(512, 2) void lstm_persistent(
    const float* __restrict__ x,      // (2,128,64)
    const float* __restrict__ Winit,  // (512,64)
    const float* __restrict__ binit,  // (512,)
    const float* __restrict__ lastf,  // (128,512)
    const ushort* __restrict__ wcat,  // [2][2048][1024] bf16
    const float* __restrict__ bc,     // [2][2048]
    ushort* __restrict__ hst,         // [2][2][128][512] bf16 (slot=t&1; init slot 1)
    ushort* __restrict__ lfbuf,       // [128][512] bf16
    unsigned* __restrict__ gcnt,      // [8][32] dwords: one counter per group, line-isolated
    float* __restrict__ out)          // (512,128,512) raw-reshape target
{
    const int tid  = threadIdx.x;
    const int lane = tid & 63;
    const int wave = tid >> 6;        // 0..7
    const int myL  = wave >> 2;       // layer this wave serves
    const int kq   = wave & 3;        // K-quarter of [inp(512) || h(512)]
    const int g    = blockIdx.x & 7;  // batch group
    const int ft   = blockIdx.x >> 3; // feature tile 0..31

    const int r16 = (tid >> 4) & 15;  // epilogue batch row within group
    const int cc  = tid & 15;         // epilogue f col within tile
    const int myB = g * 16 + r16;
    const int myF = ft * 16 + cc;

    unsigned* gc = gcnt + g * 32;     // this group's counter (own cache line)

    __shared__ float part[2][4][4][16][16];   // [parity][kq][gate][m][n]

    // ---- prologue: initial c/h, lf convert, bias, pinned weight frags ----
    float c_reg;
    {
        const float* xr = x + ((size_t)myL * BATCH + myB) * 64;
        const float* wr = Winit + (size_t)myF * 64;
        float s = binit[myF];
        #pragma unroll
        for (int k = 0; k < 64; ++k) s += xr[k] * wr[k];
        c_reg = s;
        unsigned hv = f32_to_bf16(s);
        unsigned up = (unsigned)__shfl_xor((int)hv, 1);
        if (!(cc & 1))
            astore32((unsigned*)(hst + (((size_t)myL * 2 + 1) * BATCH + myB) * FDIM + myF),
                     hv | (up << 16));
    }
    if (myL == 0) {
        float v = lastf[(size_t)myB * FDIM + myF];
        unsigned hv = f32_to_bf16(v);
        unsigned up = (unsigned)__shfl_xor((int)hv, 1);
        if (!(cc & 1))
            astore32((unsigned*)(lfbuf + (size_t)myB * FDIM + myF), hv | (up << 16));
    }
    float bias[4];
    #pragma unroll
    for (int ct = 0; ct < 4; ++ct) bias[ct] = bc[myL * GDIM + ct * FDIM + myF];

    bf16x8 bw[4][8];                                   // 128 regs of weights (VGPR/AGPR)
    {
        const int wl = lane & 15, kg0 = lane >> 4;
        #pragma unroll
        for (int ct = 0; ct < 4; ++ct) {
            const ushort* base = wcat + ((size_t)myL * GDIM + ct * FDIM + ft * 16 + wl) * 1024
                               + kq * 256 + kg0 * 8;
            #pragma unroll
            for (int ks = 0; ks < 8; ++ks)
                bw[ct][ks] = *reinterpret_cast<const bf16x8*>(base + ks * 32);
        }
    }
    #pragma unroll
    for (int ct = 0; ct < 4; ++ct)
        #pragma unroll
        for (int ks = 0; ks < 8; ++ks)
            asm volatile("" : "+v"(bw[ct][ks]));       // pin: no remat

    __syncthreads();                                   // drains the init stores
    if (tid == 0)
        __hip_atomic_fetch_add(gc, 4u, __ATOMIC_RELAXED, __HIP_MEMORY_SCOPE_AGENT);

    const int rA = lane & 15, kg = lane >> 4;

    // ---- 1024 serial phases ----
    for (int ph = 0; ph < NPH; ++ph) {
        const int L = ph & 1;
        const int t = ph >> 1;
        const bool active = (myL == L);
        const int pb = ph & 1;

        if (active) {
            const ushort* srcBase = (kq < 2)
                ? ((ph == 0) ? lfbuf
                   : (L == 0 ? hst + (size_t)(2 + ((t - 1) & 1)) * SLOT      // h1[t-1]
                             : hst + (size_t)(t & 1) * SLOT))                // h0[t]
                : (hst + (size_t)(L * 2 + ((t - 1) & 1)) * SLOT);            // own, 2 phases old
            const ushort* arow = srcBase + (size_t)(g * 16 + rA) * FDIM + (kq & 1) * 256 + kg * 8;

            // gate: inp waves poll the group counter; own waves are
            // transitively gated (except ph==0: init data)
            if (kq < 2 || ph == 0) {
                const unsigned tgt = 128u * (unsigned)(ph + 1);
                while (aload32(gc) < tgt) {}
            }

            bf16x8 af[8];
            #pragma unroll
            for (int ks = 0; ks < 8; ++ks) {
                AfU u;
                u.q[0] = aload64((const unsigned long long*)(arow + ks * 32));
                u.q[1] = aload64((const unsigned long long*)(arow + ks * 32) + 1);
                af[ks] = u.v;
            }
            f32x4 acc[4] = {{0,0,0,0},{0,0,0,0},{0,0,0,0},{0,0,0,0}};
            #pragma unroll
            for (int ks = 0; ks < 8; ++ks) {
                #pragma unroll
                for (int ct = 0; ct < 4; ++ct)
                    acc[ct] = __builtin_amdgcn_mfma_f32_16x16x32_bf16(af[ks], bw[ct][ks], acc[ct], 0, 0, 0);
            }
            const int n = lane & 15, q = lane >> 4;    // C map: m=q*4+j (batch), n (fcol)
            #pragma unroll
            for (int ct = 0; ct < 4; ++ct)
                #pragma unroll
                for (int j = 0; j < 4; ++j)
                    part[pb][kq][ct][q * 4 + j][n] = acc[ct][j];
        }
        __syncthreads();                               // the ONLY barrier this phase

        if (active) {
            float gate[4];
            #pragma unroll
            for (int ct = 0; ct < 4; ++ct)
                gate[ct] = bias[ct] + part[pb][0][ct][r16][cc] + part[pb][1][ct][r16][cc]
                         + part[pb][2][ct][r16][cc] + part[pb][3][ct][r16][cc];
            float ig = fsigmoid(gate[0]);
            float fg = fsigmoid(gate[1]);
            float gg = ftanh(gate[2]);
            float og = fsigmoid(gate[3]);
            float cn = fg * c_reg + ig * gg;
            float hn = og * ftanh(cn);
            c_reg = cn;
            unsigned hv = f32_to_bf16(hn);
            unsigned up = (unsigned)__shfl_xor((int)hv, 1);
            if (!(cc & 1))
                astore32((unsigned*)(hst + ((size_t)(L * 2 + (t & 1)) * BATCH + myB) * FDIM + myF),
                         hv | (up << 16));
            asm volatile("s_waitcnt vmcnt(0)" ::: "memory");   // my h-stores committed
            if (lane == 0)
                __hip_atomic_fetch_add(gc, 1u, __ATOMIC_RELAXED, __HIP_MEMORY_SCOPE_AGENT);
            // out-store after the signal: off the inter-WG critical path
            if (L == 1) out[((size_t)t * BATCH + myB) * FDIM + myF] = hn;
        }
    }
}

// ---------------------------------------------------------------------------
extern "C" void kernel_launch(void* const* d_in, const int* in_sizes, int n_in,
                              void* d_out, int out_size, void* d_ws, size_t ws_size,
                              hipStream_t stream)
{
    const float* x      = (const float*)d_in[0];
    const float* lastf  = (const float*)d_in[1];
    const float* W_init = (const float*)d_in[2];
    const float* b_init = (const float*)d_in[3];
    const float* W_ih0  = (const float*)d_in[4];
    const float* W_hh0  = (const float*)d_in[5];
    const float* b_ih0  = (const float*)d_in[6];
    const float* b_hh0  = (const float*)d_in[7];
    const float* W_ih1  = (const float*)d_in[8];
    const float* W_hh1  = (const float*)d_in[9];
    const float* b_ih1  = (const float*)d_in[10];
    const float* b_hh1  = (const float*)d_in[11];
    // d_in[12..13] = W_out/b_out: dead code in the reference.
    float* out = (float*)d_out;

    char* ws = (char*)d_ws;
    size_t off = 0;
    ushort*   wcat = (ushort*)(ws + off);   off += (size_t)2 * GDIM * 1024 * 2;      // 8 MB
    float*    bcb  = (float*)(ws + off);    off += (size_t)2 * GDIM * 4;             // 16 KB
    ushort*   hstb = (ushort*)(ws + off);   off += (size_t)2 * 2 * BATCH * FDIM * 2; // 512 KB
    ushort*   lfb  = (ushort*)(ws + off);   off += (size_t)BATCH * FDIM * 2;         // 128 KB
    unsigned* gcnt = (unsigned*)(ws + off); off += (size_t)8 * 32 * 4;               // 1 KB

    hipMemsetAsync(gcnt, 0, (size_t)8 * 32 * 4, stream);

    convert_weights<<<(2 * GDIM * 1024 + 255) / 256, 256, 0, stream>>>(
        W_ih0, W_hh0, W_ih1, W_hh1, b_ih0, b_hh0, b_ih1, b_hh1, wcat, bcb);

    lstm_persistent<<<256, 512, 0, stream>>>(
        x, W_init, b_init, lastf, wcat, bcb, hstb, lfb, gcnt, out);
}

// Round 11
// 3349.987 us; speedup vs baseline: 1.9614x; 1.9522x over previous
//
#include <hip/hip_runtime.h>
#include <hip/hip_bf16.h>

// L=2, B=128, T=512, D=64, F=512
#define FDIM   512
#define BATCH  128
#define TSTEPS 512
#define GDIM   2048
#define NPH    (2*TSTEPS)

typedef __attribute__((ext_vector_type(8))) short bf16x8;   // 8 bf16 (4 VGPR) MFMA A/B frag
typedef __attribute__((ext_vector_type(4))) float f32x4;    // MFMA C/D frag

union AfU { bf16x8 v; unsigned long long q[2]; };

__device__ __forceinline__ ushort f32_to_bf16(float v) {
    union { float f; unsigned u; } c; c.f = v;
    unsigned b = c.u;
    return (ushort)((b + 0x7FFFu + ((b >> 16) & 1u)) >> 16);   // RNE
}
// Fast gate nonlinearities (validated r10: absmax identical to libm at bf16).
__device__ __forceinline__ float fsigmoid(float x) {
    return __fdividef(1.0f, 1.0f + __expf(-x));
}
__device__ __forceinline__ float ftanh(float x) {
    return 1.0f - __fdividef(2.0f, __expf(2.0f * x) + 1.0f);
}

// Relaxed agent-scope (device-coherent) ops — round-4-proven sync substrate.
__device__ __forceinline__ unsigned long long aload64(const unsigned long long* p) {
    return __hip_atomic_load(p, __ATOMIC_RELAXED, __HIP_MEMORY_SCOPE_AGENT);
}
__device__ __forceinline__ unsigned aload32(const unsigned* p) {
    return __hip_atomic_load(p, __ATOMIC_RELAXED, __HIP_MEMORY_SCOPE_AGENT);
}
__device__ __forceinline__ void astore32(unsigned* p, unsigned v) {
    __hip_atomic_store(p, v, __ATOMIC_RELAXED, __HIP_MEMORY_SCOPE_AGENT);
}

// ---------------------------------------------------------------------------
// One-time: weights -> bf16 concat layout wcat[L][2048][1024] (Wih row || Whh row),
// combined bias bc[L][2048].
// ---------------------------------------------------------------------------
__global__ __launch_bounds__(256) void convert_weights(
    const float* __restrict__ Wih0, const float* __restrict__ Whh0,
    const float* __restrict__ Wih1, const float* __restrict__ Whh1,
    const float* __restrict__ bih0, const float* __restrict__ bhh0,
    const float* __restrict__ bih1, const float* __restrict__ bhh1,
    ushort* __restrict__ wcat, float* __restrict__ bc)
{
    int idx = blockIdx.x * 256 + threadIdx.x;          // covers 2*2048*1024
    if (idx < 2 * GDIM * 1024) {
        int kk = idx & 1023;
        int r  = (idx >> 10) & 2047;
        int L  = idx >> 21;
        const float* Wih = L ? Wih1 : Wih0;
        const float* Whh = L ? Whh1 : Whh0;
        float v = (kk < 512) ? Wih[(size_t)r * 512 + kk] : Whh[(size_t)r * 512 + (kk - 512)];
        wcat[idx] = f32_to_bf16(v);
    }
    if (idx < 2 * GDIM) {
        int L = idx >> 11, r = idx & 2047;
        bc[idx] = L ? (bih1[r] + bhh1[r]) : (bih0[r] + bhh0[r]);
    }
}

// ---------------------------------------------------------------------------
// Persistent 2-layer LSTM. 256 WGs x 512 threads, 1 WG/CU.
//   WG = (g = blockIdx&7: batch group of 16 rows, ft: 16 f-cols)
//   waves 0-3 layer 0, waves 4-7 layer 1; wave kq = K-quarter of [inp||h].
//   Weights: bw[4][8] = 128 regs/lane, asm-pinned. c-state: 1 reg/thread.
//   Sync per phase (round-4-proven, UNCHANGED): per-WG monotonic flag
//   (store by tid0 after a full __syncthreads), wave0 polls the group's 32
//   flags with one 32-lane load; all shared state via relaxed agent-scope
//   atomics. Changes vs r4: out-store AFTER the flag (its HBM drain
//   overlaps the next phase's poll) and fast transcendentals.
// ---------------------------------------------------------------------------
__global__ __launch_bounds__(512, 2) void lstm_persistent(
    const float* __restrict__ x,      // (2,128,64)
    const float* __restrict__ Winit,  // (512,64)
    const float* __restrict__ binit,  // (512,)
    const float* __restrict__ lastf,  // (128,512)
    const ushort* __restrict__ wcat,  // [2][2048][1024] bf16
    const float* __restrict__ bc,     // [2][2048]
    ushort* __restrict__ hst,         // [2][2][128][512] bf16 (slot=t&1; init slot 1)
    ushort* __restrict__ lfbuf,       // [128][512] bf16
    unsigned* __restrict__ flags,     // [256]: per-WG completed-phase count + 1
    float* __restrict__ out)          // (512,128,512) raw-reshape target
{
    const int tid  = threadIdx.x;
    const int lane = tid & 63;
    const int wave = tid >> 6;        // 0..7
    const int myL  = wave >> 2;       // layer this wave serves
    const int kq   = wave & 3;        // K-quarter of [inp(512) || h(512)]
    const int g    = blockIdx.x & 7;  // batch group
    const int ft   = blockIdx.x >> 3; // feature tile 0..31
    const int wgid = g * 32 + ft;

    const int r16 = (tid >> 4) & 15;  // epilogue batch row within group
    const int cc  = tid & 15;         // epilogue f col within tile
    const int myB = g * 16 + r16;
    const int myF = ft * 16 + cc;

    __shared__ float part[4][4][16][16];   // [kq][gate][m][n] — r4 layout (unpadded)

    // ---- prologue: initial c/h, lf convert, bias, pinned weight frags ----
    float c_reg;
    {
        const float* xr = x + ((size_t)myL * BATCH + myB) * 64;
        const float* wr = Winit + (size_t)myF * 64;
        float s = binit[myF];
        #pragma unroll
        for (int k = 0; k < 64; ++k) s += xr[k] * wr[k];
        c_reg = s;
        unsigned hv = f32_to_bf16(s);
        unsigned up = (unsigned)__shfl_xor((int)hv, 1);
        if (!(cc & 1))
            astore32((unsigned*)(hst + (((size_t)myL * 2 + 1) * BATCH + myB) * FDIM + myF),
                     hv | (up << 16));
    }
    if (myL == 0) {
        float v = lastf[(size_t)myB * FDIM + myF];
        unsigned hv = f32_to_bf16(v);
        unsigned up = (unsigned)__shfl_xor((int)hv, 1);
        if (!(cc & 1))
            astore32((unsigned*)(lfbuf + (size_t)myB * FDIM + myF), hv | (up << 16));
    }
    float bias[4];
    #pragma unroll
    for (int ct = 0; ct < 4; ++ct) bias[ct] = bc[myL * GDIM + ct * FDIM + myF];

    bf16x8 bw[4][8];                                   // 128 regs of weights (VGPR/AGPR)
    {
        const int wl = lane & 15, kg0 = lane >> 4;
        #pragma unroll
        for (int ct = 0; ct < 4; ++ct) {
            const ushort* base = wcat + ((size_t)myL * GDIM + ct * FDIM + ft * 16 + wl) * 1024
                               + kq * 256 + kg0 * 8;
            #pragma unroll
            for (int ks = 0; ks < 8; ++ks)
                bw[ct][ks] = *reinterpret_cast<const bf16x8*>(base + ks * 32);
        }
    }
    #pragma unroll
    for (int ct = 0; ct < 4; ++ct)
        #pragma unroll
        for (int ks = 0; ks < 8; ++ks)
            asm volatile("" : "+v"(bw[ct][ks]));       // pin: no remat

    __syncthreads();                                   // drains the init stores
    if (tid == 0) astore32(&flags[wgid], 1u);          // "0 phases complete"

    const int rA = lane & 15, kg = lane >> 4;

    // ---- 1024 serial phases ----
    for (int ph = 0; ph < NPH; ++ph) {
        const int L = ph & 1;
        const int t = ph >> 1;
        const bool active = (myL == L);

        const ushort* srcInp = (L == 0)
            ? (t == 0 ? lfbuf : hst + (size_t)(2 + ((t - 1) & 1)) * BATCH * FDIM)   // h1[t-1]
            : (hst + (size_t)(t & 1) * BATCH * FDIM);                               // h0[t]
        const ushort* srcOwn = hst + (size_t)(L * 2 + ((t - 1) & 1)) * BATCH * FDIM;
        const ushort* arow = ((kq < 2) ? srcInp : srcOwn)
                           + (size_t)(g * 16 + rA) * FDIM + (kq & 1) * 256 + kg * 8;

        bf16x8 af[8];
        // Own-h half is >=2 phases old -> visible since the PREVIOUS gate; load
        // before this phase's gate to overlap the poll. (ph==0: init not yet
        // gated -> load after.)
        const bool pre = active && (kq >= 2) && (ph > 0);
        if (pre) {
            #pragma unroll
            for (int ks = 0; ks < 8; ++ks) {
                AfU u;
                u.q[0] = aload64((const unsigned long long*)(arow + ks * 32));
                u.q[1] = aload64((const unsigned long long*)(arow + ks * 32) + 1);
                af[ks] = u.v;
            }
        }

        // gate: all 32 WGs of the group finished phase ph-1
        if (wave == 0) {
            const unsigned tgt = (unsigned)(ph + 1);
            for (;;) {
                unsigned v = (lane < 32) ? aload32(&flags[g * 32 + lane]) : tgt;
                if (__all((int)(v >= tgt))) break;
            }
        }
        __syncthreads();

        if (active) {
            if (!pre) {
                #pragma unroll
                for (int ks = 0; ks < 8; ++ks) {
                    AfU u;
                    u.q[0] = aload64((const unsigned long long*)(arow + ks * 32));
                    u.q[1] = aload64((const unsigned long long*)(arow + ks * 32) + 1);
                    af[ks] = u.v;
                }
            }
            f32x4 acc[4] = {{0,0,0,0},{0,0,0,0},{0,0,0,0},{0,0,0,0}};
            #pragma unroll
            for (int ks = 0; ks < 8; ++ks) {
                #pragma unroll
                for (int ct = 0; ct < 4; ++ct)
                    acc[ct] = __builtin_amdgcn_mfma_f32_16x16x32_bf16(af[ks], bw[ct][ks], acc[ct], 0, 0, 0);
            }
            const int n = lane & 15, q = lane >> 4;    // C map: m=q*4+j (batch), n (fcol)
            #pragma unroll
            for (int ct = 0; ct < 4; ++ct)
                #pragma unroll
                for (int j = 0; j < 4; ++j)
                    part[kq][ct][q * 4 + j][n] = acc[ct][j];
        }
        __syncthreads();

        float hn = 0.0f;
        if (active) {
            float gate[4];
            #pragma unroll
            for (int ct = 0; ct < 4; ++ct)
                gate[ct] = bias[ct] + part[0][ct][r16][cc] + part[1][ct][r16][cc]
                         + part[2][ct][r16][cc] + part[3][ct][r16][cc];
            float ig = fsigmoid(gate[0]);
            float fg = fsigmoid(gate[1]);
            float gg = ftanh(gate[2]);
            float og = fsigmoid(gate[3]);
            float cn = fg * c_reg + ig * gg;
            hn = og * ftanh(cn);
            c_reg = cn;
            unsigned hv = f32_to_bf16(hn);
            unsigned up = (unsigned)__shfl_xor((int)hv, 1);
            if (!(cc & 1))
                astore32((unsigned*)(hst + ((size_t)(L * 2 + (t & 1)) * BATCH + myB) * FDIM + myF),
                         hv | (up << 16));
        }
        __syncthreads();                               // drains h-stores WG-wide
        if (tid == 0) astore32(&flags[wgid], (unsigned)(ph + 2));
        // out-store AFTER the flag: its HBM drain overlaps the next phase's
        // poll (wave0, the poller, never carries out-stores).
        if (active && L == 1) out[((size_t)t * BATCH + myB) * FDIM + myF] = hn;
    }
}

// ---------------------------------------------------------------------------
extern "C" void kernel_launch(void* const* d_in, const int* in_sizes, int n_in,
                              void* d_out, int out_size, void* d_ws, size_t ws_size,
                              hipStream_t stream)
{
    const float* x      = (const float*)d_in[0];
    const float* lastf  = (const float*)d_in[1];
    const float* W_init = (const float*)d_in[2];
    const float* b_init = (const float*)d_in[3];
    const float* W_ih0  = (const float*)d_in[4];
    const float* W_hh0  = (const float*)d_in[5];
    const float* b_ih0  = (const float*)d_in[6];
    const float* b_hh0  = (const float*)d_in[7];
    const float* W_ih1  = (const float*)d_in[8];
    const float* W_hh1  = (const float*)d_in[9];
    const float* b_ih1  = (const float*)d_in[10];
    const float* b_hh1  = (const float*)d_in[11];
    // d_in[12..13] = W_out/b_out: dead code in the reference.
    float* out = (float*)d_out;

    char* ws = (char*)d_ws;
    size_t off = 0;
    ushort*   wcat  = (ushort*)(ws + off);   off += (size_t)2 * GDIM * 1024 * 2;      // 8 MB
    float*    bcb   = (float*)(ws + off);    off += (size_t)2 * GDIM * 4;             // 16 KB
    ushort*   hstb  = (ushort*)(ws + off);   off += (size_t)2 * 2 * BATCH * FDIM * 2; // 512 KB
    ushort*   lfb   = (ushort*)(ws + off);   off += (size_t)BATCH * FDIM * 2;         // 128 KB
    unsigned* flags = (unsigned*)(ws + off); off += 256 * 4;                          // 1 KB

    hipMemsetAsync(flags, 0, 256 * 4, stream);

    convert_weights<<<(2 * GDIM * 1024 + 255) / 256, 256, 0, stream>>>(
        W_ih0, W_hh0, W_ih1, W_hh1, b_ih0, b_hh0, b_ih1, b_hh1, wcat, bcb);

    lstm_persistent<<<256, 512, 0, stream>>>(
        x, W_init, b_init, lastf, wcat, bcb, hstb, lfb, flags, out);
}